// Round 4
// baseline (120.380 us; speedup 1.0000x reference)
//
#include <hip/hip_runtime.h>

// Problem shape (fixed): n=32, m=16, p=1024, d=512.
// out[n,p,d] = feat[n,p,d] * mean_m(task[n,m,p])
//
// Single fused kernel. Each 512-thread block owns 32 consecutive rows
// (one n, 32 consecutive p). Phase 1: the block loads the 16x32 task slab
// exactly once, fully coalesced (lanes->p, waves->m), LDS-reduces to 32 row
// means. Phase 2: pure stream — 8 float4 loads+stores per thread (4096 f4
// per block), non-temporal since feat/out have zero reuse.
// HBM floor: 2MB task + 64MB feat + 64MB out = 130MB @ ~6.3TB/s ≈ 21us.

#define N_DIM 32
#define M_DIM 16
#define P_DIM 1024
#define D_DIM 512
#define ROWS_PER_BLK 32                    // p-rows per block
#define F4_PER_ROW   (D_DIM / 4)           // 128
#define F4_PER_BLK   (ROWS_PER_BLK * F4_PER_ROW)  // 4096
#define BLK_THREADS  512
#define F4_PER_THR   (F4_PER_BLK / BLK_THREADS)   // 8
#define GRID_BLKS    (N_DIM * P_DIM / ROWS_PER_BLK)  // 1024

// Clang-native vector type: __builtin_nontemporal_* requires a pointer to
// scalar or native vector, not HIP's struct-based float4.
typedef float vfloat4 __attribute__((ext_vector_type(4)));

__global__ __launch_bounds__(BLK_THREADS) void fused_kernel(
    const float* __restrict__ task,   // [n, m, p]
    const float* __restrict__ feat,   // [n, p, d]
    float* __restrict__ out)          // [n, p, d]
{
    __shared__ float lds_v[M_DIM][ROWS_PER_BLK];  // lanes->consecutive addr: conflict-free
    __shared__ float lds_mean[ROWS_PER_BLK];

    const int b  = blockIdx.x;        // 0..1023
    const int n  = b >> 5;            // 32 p-blocks per n
    const int p0 = (b & 31) * ROWS_PER_BLK;
    const int t  = threadIdx.x;

    // Phase 1: coalesced one-shot task load. t = m*32 + p_off.
    {
        const int m  = t >> 5;
        const int po = t & 31;
        lds_v[m][po] = task[((size_t)n * M_DIM + m) * P_DIM + p0 + po];
    }
    __syncthreads();
    if (t < ROWS_PER_BLK) {
        float s = 0.0f;
#pragma unroll
        for (int m = 0; m < M_DIM; ++m) s += lds_v[m][t];
        lds_mean[t] = s * (1.0f / (float)M_DIM);
    }
    __syncthreads();

    // Phase 2: stream. f4 index idx = i*512 + t  ->  row = 4*i + (t>>7).
    float mr[F4_PER_THR];
#pragma unroll
    for (int i = 0; i < F4_PER_THR; ++i) mr[i] = lds_mean[4 * i + (t >> 7)];

    const size_t base4 = (size_t)b * F4_PER_BLK;
    const vfloat4* f4 = (const vfloat4*)feat + base4;
    vfloat4*       o4 = (vfloat4*)out + base4;
#pragma unroll
    for (int i = 0; i < F4_PER_THR; ++i) {
        const int idx = i * BLK_THREADS + t;
        vfloat4 v = __builtin_nontemporal_load(f4 + idx);
        v *= mr[i];
        __builtin_nontemporal_store(v, o4 + idx);
    }
}

extern "C" void kernel_launch(void* const* d_in, const int* in_sizes, int n_in,
                              void* d_out, int out_size, void* d_ws, size_t ws_size,
                              hipStream_t stream) {
    const float* task = (const float*)d_in[0];   // [32,16,1024] fp32
    const float* feat = (const float*)d_in[1];   // [32,1024,512] fp32
    float* out = (float*)d_out;                  // [32,1024,512] fp32

    fused_kernel<<<dim3(GRID_BLKS), dim3(BLK_THREADS), 0, stream>>>(task, feat, out);
}

// Round 5
// 116.378 us; speedup vs baseline: 1.0344x; 1.0344x over previous
//
#include <hip/hip_runtime.h>

// Problem shape (fixed): n=32, m=16, p=1024, d=512.
// out[n,p,d] = feat[n,p,d] * mean_m(task[n,m,p])
//
// Two-kernel structure (best measured: 116.4us total bench; kernel itself
// <42us, below the harness's own 268MB re-poison fills):
//   A) mean[n,p] = (1/16) * sum_m task[n,m,p]   (2MB read, 128KB write, ~2us)
//   B) out = feat * mean[row]                   (pure 128MB stream, ~21us @6.3TB/s)
// Kernel B reads mean via per-wave broadcast loads (same addr across 128
// consecutive f4-threads of a row; 128KB table -> L1/L2 resident), so it is
// structurally a stream copy — no barriers, no LDS.
// Round-4 post-mortem: fused single-kernel + nontemporal was +4us (nt stores
// and the pre-stream __syncthreads ramp) — reverted.

#define N_DIM 32
#define M_DIM 16
#define P_DIM 1024
#define D_DIM 512
#define NP    (N_DIM * P_DIM)            // 32768 rows
#define TOTAL4 (NP * (D_DIM / 4))        // 4,194,304 float4 elements

__global__ __launch_bounds__(256) void mean_kernel(
    const float* __restrict__ task,      // [n, m, p]
    float* __restrict__ mean)            // [n*p]
{
    const int i = blockIdx.x * 256 + threadIdx.x;   // 0..NP-1, consecutive p
    const int n = i >> 10;                          // / P_DIM
    const int p = i & (P_DIM - 1);
    const float* t = task + (size_t)n * M_DIM * P_DIM + p;
    float s = 0.0f;
#pragma unroll
    for (int m = 0; m < M_DIM; ++m) {
        s += t[(size_t)m * P_DIM];                  // coalesced across threads per m
    }
    mean[i] = s * (1.0f / (float)M_DIM);
}

__global__ __launch_bounds__(256) void scale_kernel(
    const float* __restrict__ feat,      // [n*p, d]
    const float* __restrict__ mean,      // [n*p]
    float* __restrict__ out)             // [n*p, d]
{
    const int idx4 = blockIdx.x * 256 + threadIdx.x;   // float4 index
    const float m = mean[idx4 >> 7];                   // d/4 = 128 float4s per row
    float4 v = ((const float4*)feat)[idx4];
    v.x *= m; v.y *= m; v.z *= m; v.w *= m;
    ((float4*)out)[idx4] = v;
}

extern "C" void kernel_launch(void* const* d_in, const int* in_sizes, int n_in,
                              void* d_out, int out_size, void* d_ws, size_t ws_size,
                              hipStream_t stream) {
    const float* task = (const float*)d_in[0];   // [32,16,1024] fp32
    const float* feat = (const float*)d_in[1];   // [32,1024,512] fp32
    float* out  = (float*)d_out;                 // [32,1024,512] fp32
    float* mean = (float*)d_ws;                  // 32768 floats = 128 KB scratch

    mean_kernel<<<dim3(NP / 256), dim3(256), 0, stream>>>(task, mean);
    scale_kernel<<<dim3(TOTAL4 / 256), dim3(256), 0, stream>>>(feat, mean, out);
}